// Round 1
// baseline (134.445 us; speedup 1.0000x reference)
//
#include <hip/hip_runtime.h>

// RSNorm: x (131072 x 256) f32. Reference = sequential running-stats scan;
// mathematically equivalent (to <1e-7 in output) to column mean/population-var
// then normalize. Three passes: partial column reduce -> finalize stats ->
// elementwise normalize. All deterministic (no atomics, no ws zero-init needed:
// every ws slot we read is written earlier in the same launch).

static constexpr int   D         = 256;
static constexpr int   NROWS     = 131072;
static constexpr float EPS       = 1e-5f;
static constexpr float VAR_FLOOR = 0.001f;

// ---------- Pass 1: per-block column partial sums (sum, sumsq) ----------
// Block: 256 threads = 4 row-lanes x 64 col-quads (float4). Each block owns
// rows [bid*rpb, (bid+1)*rpb). Fully coalesced float4 loads (1 KiB/wave-inst).
__global__ __launch_bounds__(256) void pass1_partials(const float* __restrict__ x,
                                                      float* __restrict__ psum,
                                                      float* __restrict__ psq,
                                                      int rows_per_blk) {
    const int tid    = threadIdx.x;
    const int col4   = tid & 63;   // which float4 of the row
    const int rowoff = tid >> 6;   // 0..3
    const float4* __restrict__ xv = (const float4*)x;
    const size_t base_row = (size_t)blockIdx.x * rows_per_blk + rowoff;

    float4 s = make_float4(0.f, 0.f, 0.f, 0.f);
    float4 q = make_float4(0.f, 0.f, 0.f, 0.f);
    const int iters = rows_per_blk >> 2;
    #pragma unroll 8
    for (int i = 0; i < iters; ++i) {
        float4 v = xv[(base_row + (size_t)i * 4) * (D / 4) + col4];
        s.x += v.x; s.y += v.y; s.z += v.z; s.w += v.w;
        q.x = fmaf(v.x, v.x, q.x);
        q.y = fmaf(v.y, v.y, q.y);
        q.z = fmaf(v.z, v.z, q.z);
        q.w = fmaf(v.w, v.w, q.w);
    }

    __shared__ float ls[4][D];
    __shared__ float lq[4][D];
    ls[rowoff][col4 * 4 + 0] = s.x;
    ls[rowoff][col4 * 4 + 1] = s.y;
    ls[rowoff][col4 * 4 + 2] = s.z;
    ls[rowoff][col4 * 4 + 3] = s.w;
    lq[rowoff][col4 * 4 + 0] = q.x;
    lq[rowoff][col4 * 4 + 1] = q.y;
    lq[rowoff][col4 * 4 + 2] = q.z;
    lq[rowoff][col4 * 4 + 3] = q.w;
    __syncthreads();

    // thread tid reduces column tid across the 4 row-lanes (conflict-free reads)
    float fs = ls[0][tid] + ls[1][tid] + ls[2][tid] + ls[3][tid];
    float fq = lq[0][tid] + lq[1][tid] + lq[2][tid] + lq[3][tid];
    psum[(size_t)blockIdx.x * D + tid] = fs;
    psq [(size_t)blockIdx.x * D + tid] = fq;
}

// ---------- Pass 2: fold partials -> mu[256], inv_std[256] ----------
__global__ __launch_bounds__(1024) void pass2_finalize(const float* __restrict__ psum,
                                                       const float* __restrict__ psq,
                                                       float* __restrict__ stats,
                                                       int nblk) {
    const int t   = threadIdx.x;
    const int col = t & 255;
    const int seg = t >> 8;        // 0..3
    const int per = nblk >> 2;
    float s = 0.f, q = 0.f;
    for (int p = seg * per; p < (seg + 1) * per; ++p) {
        s += psum[(size_t)p * D + col];
        q += psq [(size_t)p * D + col];
    }
    __shared__ float ss[4][D];
    __shared__ float sq[4][D];
    ss[seg][col] = s;
    sq[seg][col] = q;
    __syncthreads();
    if (t < D) {
        float fs = ss[0][t] + ss[1][t] + ss[2][t] + ss[3][t];
        float fq = sq[0][t] + sq[1][t] + sq[2][t] + sq[3][t];
        const float invN = 1.0f / (float)NROWS;
        float mu  = fs * invN;
        float var = fmaf(-mu, mu, fq * invN);   // E[x^2] - mu^2
        var = fmaxf(var, VAR_FLOOR);            // floor (never binds here)
        stats[t]     = mu;
        stats[D + t] = rsqrtf(var + EPS);
    }
}

// ---------- Pass 3: out = (x - mu) * inv_std ----------
// Grid-stride over float4 elements; each thread's column-quad (e % 64) is
// invariant because the stride is a multiple of 64, so stats load once.
__global__ __launch_bounds__(256) void pass3_normalize(const float* __restrict__ x,
                                                       const float* __restrict__ stats,
                                                       float* __restrict__ out) {
    const int tid  = threadIdx.x;
    const int col4 = tid & 63;
    const float4 mu4 = ((const float4*)stats)[col4];
    const float4 iv4 = ((const float4*)(stats + D))[col4];

    const size_t total = (size_t)NROWS * (D / 4);
    const size_t G     = (size_t)gridDim.x * blockDim.x;
    const float4* __restrict__ xv = (const float4*)x;
    float4* __restrict__ ov = (float4*)out;

    for (size_t e = (size_t)blockIdx.x * blockDim.x + tid; e < total; e += G) {
        float4 v = xv[e];
        float4 o;
        o.x = (v.x - mu4.x) * iv4.x;
        o.y = (v.y - mu4.y) * iv4.y;
        o.z = (v.z - mu4.z) * iv4.z;
        o.w = (v.w - mu4.w) * iv4.w;
        ov[e] = o;
    }
}

extern "C" void kernel_launch(void* const* d_in, const int* in_sizes, int n_in,
                              void* d_out, int out_size, void* d_ws, size_t ws_size,
                              hipStream_t stream) {
    const float* x   = (const float*)d_in[0];
    float*       out = (float*)d_out;
    float*       ws  = (float*)d_ws;

    // Pick pass-1 block count to fit workspace: nblk*256*2 partials + 512 stats.
    int nblk = 1024;
    while (nblk > 64 && (size_t)(nblk * 2 * D + 2 * D) * sizeof(float) > ws_size)
        nblk >>= 1;
    const int rows_per_blk = NROWS / nblk;

    float* psum  = ws;
    float* psq   = ws + (size_t)nblk * D;
    float* stats = psq + (size_t)nblk * D;

    pass1_partials<<<nblk, 256, 0, stream>>>(x, psum, psq, rows_per_blk);
    pass2_finalize<<<1, 1024, 0, stream>>>(psum, psq, stats, nblk);
    pass3_normalize<<<2048, 256, 0, stream>>>(x, stats, out);
}

// Round 2
// 70.819 us; speedup vs baseline: 1.8984x; 1.8984x over previous
//
#include <hip/hip_runtime.h>

// RSNorm: x (131072 x 256) f32. Column mean/var (mathematically equal to the
// reference's sequential running-stats scan to <1e-7), then normalize.
// Round-1 fix: pass 2 was 1 workgroup doing a serial 2 MB fold (~30-45 us of
// latency on one CU). Now: pass 1 writes partials transposed [D][nblk] so
// pass 2 can run 256 blocks (one per column) with coalesced float4 loads.

static constexpr int   D         = 256;
static constexpr int   NROWS     = 131072;
static constexpr float EPS       = 1e-5f;
static constexpr float VAR_FLOOR = 0.001f;

// ---------- Pass 1: per-block column partial sums, transposed output ----------
// Block: 256 threads = 4 row-lanes x 64 col-quads (float4). Each block owns
// rows [bid*rpb, (bid+1)*rpb). Coalesced float4 loads (1 KiB/wave-inst).
// Output layout: psum[col * nblk + bid] (scattered 4B stores, 2 KB/block).
__global__ __launch_bounds__(256) void pass1_partials(const float* __restrict__ x,
                                                      float* __restrict__ psum,
                                                      float* __restrict__ psq,
                                                      int rows_per_blk, int nblk) {
    const int tid    = threadIdx.x;
    const int col4   = tid & 63;   // which float4 of the row
    const int rowoff = tid >> 6;   // 0..3
    const float4* __restrict__ xv = (const float4*)x;
    const size_t base_row = (size_t)blockIdx.x * rows_per_blk + rowoff;

    float4 s = make_float4(0.f, 0.f, 0.f, 0.f);
    float4 q = make_float4(0.f, 0.f, 0.f, 0.f);
    const int iters = rows_per_blk >> 2;
    #pragma unroll 8
    for (int i = 0; i < iters; ++i) {
        float4 v = xv[(base_row + (size_t)i * 4) * (D / 4) + col4];
        s.x += v.x; s.y += v.y; s.z += v.z; s.w += v.w;
        q.x = fmaf(v.x, v.x, q.x);
        q.y = fmaf(v.y, v.y, q.y);
        q.z = fmaf(v.z, v.z, q.z);
        q.w = fmaf(v.w, v.w, q.w);
    }

    __shared__ float ls[4][D];
    __shared__ float lq[4][D];
    ls[rowoff][col4 * 4 + 0] = s.x;
    ls[rowoff][col4 * 4 + 1] = s.y;
    ls[rowoff][col4 * 4 + 2] = s.z;
    ls[rowoff][col4 * 4 + 3] = s.w;
    lq[rowoff][col4 * 4 + 0] = q.x;
    lq[rowoff][col4 * 4 + 1] = q.y;
    lq[rowoff][col4 * 4 + 2] = q.z;
    lq[rowoff][col4 * 4 + 3] = q.w;
    __syncthreads();

    // thread tid reduces column tid across the 4 row-lanes, writes transposed
    float fs = ls[0][tid] + ls[1][tid] + ls[2][tid] + ls[3][tid];
    float fq = lq[0][tid] + lq[1][tid] + lq[2][tid] + lq[3][tid];
    psum[(size_t)tid * nblk + blockIdx.x] = fs;
    psq [(size_t)tid * nblk + blockIdx.x] = fq;
}

// ---------- Pass 2: 256 blocks, block c folds column c -> mu, inv_std ----------
__global__ __launch_bounds__(256) void pass2_finalize(const float* __restrict__ psum,
                                                      const float* __restrict__ psq,
                                                      float* __restrict__ stats,
                                                      int nblk) {
    const int c = blockIdx.x;          // column
    const int t = threadIdx.x;
    float s = 0.f, q = 0.f;
    const int nquads = nblk >> 2;      // nblk is a power of two >= 64
    for (int i = t; i < nquads; i += 256) {
        float4 vs = ((const float4*)(psum + (size_t)c * nblk))[i];
        float4 vq = ((const float4*)(psq  + (size_t)c * nblk))[i];
        s += vs.x + vs.y + vs.z + vs.w;
        q += vq.x + vq.y + vq.z + vq.w;
    }
    // wave reduce (64 lanes)
    #pragma unroll
    for (int off = 32; off > 0; off >>= 1) {
        s += __shfl_down(s, off, 64);
        q += __shfl_down(q, off, 64);
    }
    __shared__ float ss[4], sq[4];
    if ((t & 63) == 0) { ss[t >> 6] = s; sq[t >> 6] = q; }
    __syncthreads();
    if (t == 0) {
        float fs = ss[0] + ss[1] + ss[2] + ss[3];
        float fq = sq[0] + sq[1] + sq[2] + sq[3];
        const float invN = 1.0f / (float)NROWS;
        float mu  = fs * invN;
        float var = fmaf(-mu, mu, fq * invN);   // E[x^2] - mu^2
        var = fmaxf(var, VAR_FLOOR);            // floor (never binds for N(0,1))
        stats[c]     = mu;
        stats[D + c] = rsqrtf(var + EPS);
    }
}

// ---------- Pass 3: out = (x - mu) * inv_std ----------
// Grid-stride over float4 elements; each thread's column-quad (e % 64) is
// invariant because the stride is a multiple of 64, so stats load once.
__global__ __launch_bounds__(256) void pass3_normalize(const float* __restrict__ x,
                                                       const float* __restrict__ stats,
                                                       float* __restrict__ out) {
    const int tid  = threadIdx.x;
    const int col4 = tid & 63;
    const float4 mu4 = ((const float4*)stats)[col4];
    const float4 iv4 = ((const float4*)(stats + D))[col4];

    const size_t total = (size_t)NROWS * (D / 4);
    const size_t G     = (size_t)gridDim.x * blockDim.x;
    const float4* __restrict__ xv = (const float4*)x;
    float4* __restrict__ ov = (float4*)out;

    for (size_t e = (size_t)blockIdx.x * blockDim.x + tid; e < total; e += G) {
        float4 v = xv[e];
        float4 o;
        o.x = (v.x - mu4.x) * iv4.x;
        o.y = (v.y - mu4.y) * iv4.y;
        o.z = (v.z - mu4.z) * iv4.z;
        o.w = (v.w - mu4.w) * iv4.w;
        ov[e] = o;
    }
}

extern "C" void kernel_launch(void* const* d_in, const int* in_sizes, int n_in,
                              void* d_out, int out_size, void* d_ws, size_t ws_size,
                              hipStream_t stream) {
    const float* x   = (const float*)d_in[0];
    float*       out = (float*)d_out;
    float*       ws  = (float*)d_ws;

    // Pick pass-1 block count to fit workspace: nblk*256*2 partials + 512 stats.
    int nblk = 1024;
    while (nblk > 64 && (size_t)(nblk * 2 * D + 2 * D) * sizeof(float) > ws_size)
        nblk >>= 1;
    const int rows_per_blk = NROWS / nblk;

    float* psum  = ws;
    float* psq   = ws + (size_t)nblk * D;
    float* stats = psq + (size_t)nblk * D;

    pass1_partials<<<nblk, 256, 0, stream>>>(x, psum, psq, rows_per_blk, nblk);
    pass2_finalize<<<D, 256, 0, stream>>>(psum, psq, stats, nblk);
    pass3_normalize<<<2048, 256, 0, stream>>>(x, stats, out);
}